// Round 1
// baseline (550.774 us; speedup 1.0000x reference)
//
#include <hip/hip_runtime.h>

#define N_CH 128   // IN_CH == OUT_CH == 128
#define HCH  64    // hidden = OUT_CH/2

// ---------------- CSR build ----------------

__global__ void k_zero(int* __restrict__ cnt, int n) {
    int i = blockIdx.x * blockDim.x + threadIdx.x;
    if (i < n) cnt[i] = 0;
}

__global__ void k_count(const int* __restrict__ dst, int* __restrict__ cnt, int E) {
    int e = blockIdx.x * blockDim.x + threadIdx.x;
    if (e < E) atomicAdd(&cnt[dst[e]], 1);
}

// single-block exclusive scan of cnt -> offs, cur; also dinv = rsqrt(cnt+1)
__global__ __launch_bounds__(1024) void k_scan(const int* __restrict__ cnt,
                                               int* __restrict__ offs,
                                               int* __restrict__ cur,
                                               float* __restrict__ dinv, int n) {
    __shared__ int ssum[16];
    __shared__ int sbase;
    int tid = threadIdx.x;
    int lane = tid & 63, wid = tid >> 6;
    if (tid == 0) sbase = 0;
    __syncthreads();
    for (int base = 0; base < n; base += 1024) {
        int i = base + tid;
        int v = (i < n) ? cnt[i] : 0;
        int x = v;
        #pragma unroll
        for (int off = 1; off < 64; off <<= 1) {
            int y = __shfl_up(x, off, 64);
            if (lane >= off) x += y;
        }
        if (lane == 63) ssum[wid] = x;
        __syncthreads();
        if (wid == 0 && lane < 16) {
            int s = ssum[lane];
            #pragma unroll
            for (int off = 1; off < 16; off <<= 1) {
                int y = __shfl_up(s, off, 64);
                if (lane >= off) s += y;
            }
            ssum[lane] = s;  // inclusive wave sums
        }
        __syncthreads();
        int waveoff = (wid > 0) ? ssum[wid - 1] : 0;
        int incl = x + waveoff + sbase;
        if (i < n) {
            int excl = incl - v;
            offs[i] = excl;
            cur[i]  = excl;
            dinv[i] = rsqrtf((float)(v + 1));   // deg includes self-loop
        }
        __syncthreads();
        if (tid == 1023) sbase = incl;
        __syncthreads();
    }
}

__global__ void k_fill(const int* __restrict__ src, const int* __restrict__ dst,
                       int* __restrict__ cur, int* __restrict__ csr, int E) {
    int e = blockIdx.x * blockDim.x + threadIdx.x;
    if (e < E) {
        int d = dst[e];
        int p = atomicAdd(&cur[d], 1);
        csr[p] = src[e];
    }
}

// ---------------- one hop: out[i] = dinv[i]*( dinv[i]*h[i] + sum_s dinv[s]*h[s] ) ----------------
// one wave per node; lane handles 2 features (float2)

__global__ __launch_bounds__(256) void k_hop(const float* __restrict__ hin,
                                             float* __restrict__ hout,
                                             const int* __restrict__ offs,
                                             const int* __restrict__ cnt,
                                             const float* __restrict__ dinv,
                                             const int* __restrict__ csr, int n) {
    int node = blockIdx.x * (blockDim.x >> 6) + (threadIdx.x >> 6);
    int lane = threadIdx.x & 63;
    if (node >= n) return;
    float di = dinv[node];
    const float2* row = (const float2*)(hin + (size_t)node * N_CH);
    float2 v = row[lane];
    float ax = di * v.x, ay = di * v.y;
    int s0 = offs[node];
    int c  = cnt[node];
    for (int t = 0; t < c; ++t) {
        int s = csr[s0 + t];
        float ds = dinv[s];
        const float2* r2 = (const float2*)(hin + (size_t)s * N_CH);
        float2 u = r2[lane];
        ax += ds * u.x;
        ay += ds * u.y;
    }
    float2 o;
    o.x = di * ax;
    o.y = di * ay;
    ((float2*)(hout + (size_t)node * N_CH))[lane] = o;
}

// ---------------- z = h @ W^T + b  ([n,128] @ [128,128]^T) ----------------
// block = 128 threads; thread j owns output feature j, W row j in registers;
// h row read is same-address across lanes -> broadcast from L1.

__global__ __launch_bounds__(128) void k_zlin(const float* __restrict__ h,
                                              const float* __restrict__ W,
                                              const float* __restrict__ b,
                                              float* __restrict__ z, int n) {
    int j = threadIdx.x;  // 0..127
    float wreg[N_CH];
    const float4* wr = (const float4*)(W + (size_t)j * N_CH);
    #pragma unroll
    for (int k = 0; k < N_CH / 4; ++k) ((float4*)wreg)[k] = wr[k];
    float bj = b[j];
    for (int node = blockIdx.x; node < n; node += gridDim.x) {
        const float4* hr = (const float4*)(h + (size_t)node * N_CH);
        float acc = bj;
        #pragma unroll
        for (int k = 0; k < N_CH / 4; ++k) {
            float4 hv = hr[k];
            acc += wreg[4 * k + 0] * hv.x;
            acc += wreg[4 * k + 1] * hv.y;
            acc += wreg[4 * k + 2] * hv.z;
            acc += wreg[4 * k + 3] * hv.w;
        }
        z[(size_t)node * N_CH + j] = acc;
    }
}

// ---------------- decode: r[p] = w2 . relu(W1 (z[a]*z[b]) + b1) + b2 ----------------
// one wave per pair; lane j holds W1 row j (128 regs); s staged in per-wave LDS.

__global__ __launch_bounds__(256) void k_decode(const float* __restrict__ z,
                                                const int* __restrict__ ai,
                                                const int* __restrict__ bi,
                                                const float* __restrict__ W1,
                                                const float* __restrict__ b1,
                                                const float* __restrict__ w2,
                                                const float* __restrict__ b2,
                                                float* __restrict__ out, int m) {
    __shared__ float s_s[4][N_CH];  // per-wave s buffer
    int lane = threadIdx.x & 63;
    int wid  = threadIdx.x >> 6;
    float w1reg[N_CH];
    const float4* w1r = (const float4*)(W1 + (size_t)lane * N_CH);
    #pragma unroll
    for (int k = 0; k < N_CH / 4; ++k) ((float4*)w1reg)[k] = w1r[k];
    float b1j = b1[lane];
    float w2j = w2[lane];
    float b2v = b2[0];
    int gw = blockIdx.x * 4 + wid;
    int nw = gridDim.x * 4;
    for (int p = gw; p < m; p += nw) {
        int ia = ai[p], ib = bi[p];
        const float2* za = (const float2*)(z + (size_t)ia * N_CH);
        const float2* zb = (const float2*)(z + (size_t)ib * N_CH);
        float2 va = za[lane];
        float2 vb = zb[lane];
        s_s[wid][2 * lane + 0] = va.x * vb.x;
        s_s[wid][2 * lane + 1] = va.y * vb.y;
        __builtin_amdgcn_wave_barrier();  // intra-wave LDS ordering (compiler fence)
        float acc = b1j;
        #pragma unroll
        for (int k = 0; k < N_CH / 4; ++k) {
            float4 sv = ((const float4*)s_s[wid])[k];
            acc += w1reg[4 * k + 0] * sv.x;
            acc += w1reg[4 * k + 1] * sv.y;
            acc += w1reg[4 * k + 2] * sv.z;
            acc += w1reg[4 * k + 3] * sv.w;
        }
        __builtin_amdgcn_wave_barrier();
        float h1 = fmaxf(acc, 0.0f) * w2j;
        #pragma unroll
        for (int off = 32; off > 0; off >>= 1) h1 += __shfl_down(h1, off, 64);
        if (lane == 0) out[p] = h1 + b2v;
    }
}

// ---------------- launch ----------------

extern "C" void kernel_launch(void* const* d_in, const int* in_sizes, int n_in,
                              void* d_out, int out_size, void* d_ws, size_t ws_size,
                              hipStream_t stream) {
    const float* x   = (const float*)d_in[0];
    const int*   ei  = (const int*)d_in[1];
    const int*   eli = (const int*)d_in[2];
    const float* W   = (const float*)d_in[3];
    const float* bc  = (const float*)d_in[4];
    const float* W1  = (const float*)d_in[5];
    const float* b1  = (const float*)d_in[6];
    const float* w2  = (const float*)d_in[7];
    const float* b2  = (const float*)d_in[8];
    float* out = (float*)d_out;

    const int N = in_sizes[0] / N_CH;   // 50000
    const int E = in_sizes[1] / 2;      // 600000
    const int M = in_sizes[2] / 2;      // 200000

    const int* src = ei;
    const int* dst = ei + E;
    const int* ai  = eli;
    const int* bi  = eli + M;

    // workspace layout (fp32/int32 elements)
    float* hA  = (float*)d_ws;            // N*128
    float* hB  = hA + (size_t)N * N_CH;   // N*128
    int*   csr = (int*)(hB + (size_t)N * N_CH);  // E
    int*   cnt = csr + E;                 // N
    int*   off = cnt + N;                 // N
    int*   cur = off + N;                 // N
    float* dnv = (float*)(cur + N);       // N

    // 1) CSR by dst
    k_zero<<<(N + 255) / 256, 256, 0, stream>>>(cnt, N);
    k_count<<<(E + 255) / 256, 256, 0, stream>>>(dst, cnt, E);
    k_scan<<<1, 1024, 0, stream>>>(cnt, off, cur, dnv, N);
    k_fill<<<(E + 255) / 256, 256, 0, stream>>>(src, dst, cur, csr, E);

    // 2) two propagation hops (wave per node, 4 nodes/block)
    int hop_blocks = (N + 3) / 4;
    k_hop<<<hop_blocks, 256, 0, stream>>>(x,  hA, off, cnt, dnv, csr, N);
    k_hop<<<hop_blocks, 256, 0, stream>>>(hA, hB, off, cnt, dnv, csr, N);

    // 3) z = hB @ W^T + bc   (written into hA)
    k_zlin<<<2048, 128, 0, stream>>>(hB, W, bc, hA, N);

    // 4) decode
    k_decode<<<2048, 256, 0, stream>>>(hA, ai, bi, W1, b1, w2, b2, out, M);
}

// Round 2
// 406.377 us; speedup vs baseline: 1.3553x; 1.3553x over previous
//
#include <hip/hip_runtime.h>

#define N_CH 128   // IN_CH == OUT_CH == 128
#define HCH  64    // hidden = OUT_CH/2

// ---------------- CSR build ----------------

__global__ void k_zero(int* __restrict__ cnt, int n) {
    int i = blockIdx.x * blockDim.x + threadIdx.x;
    if (i < n) cnt[i] = 0;
}

__global__ void k_count(const int* __restrict__ dst, int* __restrict__ cnt, int E) {
    int e = blockIdx.x * blockDim.x + threadIdx.x;
    if (e < E) atomicAdd(&cnt[dst[e]], 1);
}

// single-block exclusive scan of cnt -> offs, cur; also dinv = rsqrt(cnt+1)
__global__ __launch_bounds__(1024) void k_scan(const int* __restrict__ cnt,
                                               int* __restrict__ offs,
                                               int* __restrict__ cur,
                                               float* __restrict__ dinv, int n) {
    __shared__ int ssum[16];
    __shared__ int sbase;
    int tid = threadIdx.x;
    int lane = tid & 63, wid = tid >> 6;
    if (tid == 0) sbase = 0;
    __syncthreads();
    for (int base = 0; base < n; base += 1024) {
        int i = base + tid;
        int v = (i < n) ? cnt[i] : 0;
        int x = v;
        #pragma unroll
        for (int off = 1; off < 64; off <<= 1) {
            int y = __shfl_up(x, off, 64);
            if (lane >= off) x += y;
        }
        if (lane == 63) ssum[wid] = x;
        __syncthreads();
        if (wid == 0 && lane < 16) {
            int s = ssum[lane];
            #pragma unroll
            for (int off = 1; off < 16; off <<= 1) {
                int y = __shfl_up(s, off, 64);
                if (lane >= off) s += y;
            }
            ssum[lane] = s;  // inclusive wave sums
        }
        __syncthreads();
        int waveoff = (wid > 0) ? ssum[wid - 1] : 0;
        int incl = x + waveoff + sbase;
        if (i < n) {
            int excl = incl - v;
            offs[i] = excl;
            cur[i]  = excl;
            dinv[i] = rsqrtf((float)(v + 1));   // deg includes self-loop
        }
        __syncthreads();
        if (tid == 1023) sbase = incl;
        __syncthreads();
    }
}

// fill packed (src_index, src_weight) pairs
__global__ void k_fill(const int* __restrict__ src, const int* __restrict__ dst,
                       int* __restrict__ cur, const float* __restrict__ dinv,
                       int2* __restrict__ csr2, int E) {
    int e = blockIdx.x * blockDim.x + threadIdx.x;
    if (e < E) {
        int d = dst[e];
        int s = src[e];
        int p = atomicAdd(&cur[d], 1);
        int2 pk;
        pk.x = s;
        pk.y = __float_as_int(dinv[s]);
        csr2[p] = pk;
    }
}

// ---------------- one hop ----------------
// out[i] = dinv[i]*( dinv[i]*h[i] + sum_s dinv[s]*h[s] )
// wave per node, lane = 2 features; 8-deep batched neighbor prefetch.

__global__ __launch_bounds__(256) void k_hop(const float* __restrict__ hin,
                                             float* __restrict__ hout,
                                             const int* __restrict__ offs,
                                             const int* __restrict__ cnt,
                                             const float* __restrict__ dinv,
                                             const int2* __restrict__ csr2, int n) {
    int node = blockIdx.x * 4 + (threadIdx.x >> 6);
    int lane = threadIdx.x & 63;
    if (node >= n) return;
    float di = dinv[node];
    float2 v = ((const float2*)(hin + (size_t)node * N_CH))[lane];
    float ax = di * v.x, ay = di * v.y;
    int s0 = offs[node];
    int c  = cnt[node];
    const int2* lst = csr2 + s0;
    for (int t = 0; t < c; t += 8) {
        int2 e[8];
        #pragma unroll
        for (int i = 0; i < 8; ++i) {
            int tt = t + i;
            e[i] = lst[tt < c ? tt : c - 1];   // clamped: dup last, weight zeroed below
        }
        float2 u[8]; float wg[8];
        #pragma unroll
        for (int i = 0; i < 8; ++i) {
            u[i] = ((const float2*)(hin + (size_t)e[i].x * N_CH))[lane];
            wg[i] = (t + i < c) ? __int_as_float(e[i].y) : 0.0f;
        }
        #pragma unroll
        for (int i = 0; i < 8; ++i) {
            ax += wg[i] * u[i].x;
            ay += wg[i] * u[i].y;
        }
    }
    float2 o;
    o.x = di * ax;
    o.y = di * ay;
    ((float2*)(hout + (size_t)node * N_CH))[lane] = o;
}

// ---------------- z = h @ W^T + b : tiled fp32 GEMM ----------------
// block tile: 64 nodes x 64 out-ch; 256 threads, 4x4 register tile each.
// Both operands staged in XOR-swizzled LDS (conflict-free b128 reads).

__global__ __launch_bounds__(256) void k_zlin(const float* __restrict__ h,
                                              const float* __restrict__ W,
                                              const float* __restrict__ b,
                                              float* __restrict__ z, int n) {
    __shared__ float hs[64 * 128];
    __shared__ float ws[64 * 128];
    int tid = threadIdx.x;
    int nb = (blockIdx.x >> 1) * 64;   // node base
    int cb = (blockIdx.x & 1) * 64;    // out-channel base
    #pragma unroll
    for (int i = 0; i < 8; ++i) {       // stage h tile (reads may run past n; lands in ws scratch, discarded)
        int g = tid + 256 * i;
        int r = g >> 5, c = g & 31;
        float4 vv = ((const float4*)(h + (size_t)(nb + r) * N_CH))[c];
        ((float4*)hs)[r * 32 + (c ^ (r & 31))] = vv;
    }
    #pragma unroll
    for (int i = 0; i < 8; ++i) {       // stage W half-tile
        int g = tid + 256 * i;
        int r = g >> 5, c = g & 31;
        float4 vv = ((const float4*)(W + (size_t)(cb + r) * N_CH))[c];
        ((float4*)ws)[r * 32 + (c ^ (r & 31))] = vv;
    }
    __syncthreads();
    int pc = tid & 15, hr = tid >> 4;
    int h0 = hr * 4;
    float acc[4][4];
    #pragma unroll
    for (int i = 0; i < 4; ++i)
        #pragma unroll
        for (int j = 0; j < 4; ++j) acc[i][j] = 0.0f;
    #pragma unroll 4
    for (int kc = 0; kc < 32; ++kc) {
        float4 sv[4], wv[4];
        #pragma unroll
        for (int i = 0; i < 4; ++i) {
            int p = pc + 16 * i;
            sv[i] = ((const float4*)hs)[p * 32 + (kc ^ (p & 31))];
        }
        #pragma unroll
        for (int j = 0; j < 4; ++j) {
            int hh = h0 + j;
            wv[j] = ((const float4*)ws)[hh * 32 + (kc ^ (hh & 31))];
        }
        #pragma unroll
        for (int i = 0; i < 4; ++i)
            #pragma unroll
            for (int j = 0; j < 4; ++j)
                acc[i][j] += sv[i].x * wv[j].x + sv[i].y * wv[j].y +
                             sv[i].z * wv[j].z + sv[i].w * wv[j].w;
    }
    float4 bv = *(const float4*)(b + cb + h0);
    float bb[4] = {bv.x, bv.y, bv.z, bv.w};
    #pragma unroll
    for (int i = 0; i < 4; ++i) {
        int node = nb + pc + 16 * i;
        if (node < n) {
            float4 o;
            o.x = acc[i][0] + bb[0];
            o.y = acc[i][1] + bb[1];
            o.z = acc[i][2] + bb[2];
            o.w = acc[i][3] + bb[3];
            *(float4*)(z + (size_t)node * N_CH + cb + h0) = o;
        }
    }
}

// ---------------- decode: tiled GEMM over 64 pairs/block ----------------
// stage s = z[a]*z[b] (gather) + W1 into swizzled LDS; 4x4 register tile;
// epilogue: relu, *w2, reduce over 64 hidden, +b2.

__global__ __launch_bounds__(256) void k_decode(const float* __restrict__ z,
                                                const int* __restrict__ ai,
                                                const int* __restrict__ bi,
                                                const float* __restrict__ W1,
                                                const float* __restrict__ b1,
                                                const float* __restrict__ w2,
                                                const float* __restrict__ b2,
                                                float* __restrict__ out, int m) {
    __shared__ float s_s[64 * 128];
    __shared__ float w1s[64 * 128];
    int tid = threadIdx.x;
    int lane = tid & 63, wid = tid >> 6;
    int pbase = blockIdx.x * 64;
    #pragma unroll
    for (int i = 0; i < 8; ++i) {       // stage W1 (64x128)
        int g = tid + 256 * i;
        int r = g >> 5, c = g & 31;
        float4 vv = ((const float4*)(W1 + (size_t)r * N_CH))[c];
        ((float4*)w1s)[r * 32 + (c ^ (r & 31))] = vv;
    }
    // stage s: wave wid owns pairs wid*16..wid*16+15, 2 per iter for ILP
    {
        int cch = lane >> 1;            // float4 chunk this lane's float2 lives in
        int off = (lane & 1) * 2;       // float offset within chunk
        for (int it = 0; it < 16; it += 2) {
            int p0 = wid * 16 + it, p1 = p0 + 1;
            int g0 = pbase + p0; if (g0 > m - 1) g0 = m - 1;
            int g1 = pbase + p1; if (g1 > m - 1) g1 = m - 1;
            int ia0 = ai[g0], ib0 = bi[g0];
            int ia1 = ai[g1], ib1 = bi[g1];
            float2 a0 = ((const float2*)(z + (size_t)ia0 * N_CH))[lane];
            float2 c0 = ((const float2*)(z + (size_t)ib0 * N_CH))[lane];
            float2 a1 = ((const float2*)(z + (size_t)ia1 * N_CH))[lane];
            float2 c1 = ((const float2*)(z + (size_t)ib1 * N_CH))[lane];
            float2 s0; s0.x = a0.x * c0.x; s0.y = a0.y * c0.y;
            float2 s1; s1.x = a1.x * c1.x; s1.y = a1.y * c1.y;
            *(float2*)(s_s + p0 * 128 + (cch ^ (p0 & 31)) * 4 + off) = s0;
            *(float2*)(s_s + p1 * 128 + (cch ^ (p1 & 31)) * 4 + off) = s1;
        }
    }
    __syncthreads();
    int pc = tid & 15, hr = tid >> 4;
    int h0 = hr * 4;
    float4 b1v = *(const float4*)(b1 + h0);
    float bb[4] = {b1v.x, b1v.y, b1v.z, b1v.w};
    float acc[4][4];
    #pragma unroll
    for (int i = 0; i < 4; ++i)
        #pragma unroll
        for (int j = 0; j < 4; ++j) acc[i][j] = bb[j];
    #pragma unroll 4
    for (int kc = 0; kc < 32; ++kc) {
        float4 sv[4], wv[4];
        #pragma unroll
        for (int i = 0; i < 4; ++i) {
            int p = pc + 16 * i;
            sv[i] = ((const float4*)s_s)[p * 32 + (kc ^ (p & 31))];
        }
        #pragma unroll
        for (int j = 0; j < 4; ++j) {
            int hh = h0 + j;
            wv[j] = ((const float4*)w1s)[hh * 32 + (kc ^ (hh & 31))];
        }
        #pragma unroll
        for (int i = 0; i < 4; ++i)
            #pragma unroll
            for (int j = 0; j < 4; ++j)
                acc[i][j] += sv[i].x * wv[j].x + sv[i].y * wv[j].y +
                             sv[i].z * wv[j].z + sv[i].w * wv[j].w;
    }
    __syncthreads();   // all waves done reading s_s before reuse
    float4 w2v = *(const float4*)(w2 + h0);
    float w2a[4] = {w2v.x, w2v.y, w2v.z, w2v.w};
    #pragma unroll
    for (int i = 0; i < 4; ++i) {       // partials: part[pair][hr] into s_s reuse
        int p = pc + 16 * i;
        float pr = 0.0f;
        #pragma unroll
        for (int j = 0; j < 4; ++j) pr += w2a[j] * fmaxf(acc[i][j], 0.0f);
        s_s[p * 16 + hr] = pr;
    }
    __syncthreads();
    if (tid < 64) {
        float r = b2[0];
        const float4* pp = (const float4*)(s_s + tid * 16);
        float4 q0 = pp[0], q1 = pp[1], q2 = pp[2], q3 = pp[3];
        r += q0.x + q0.y + q0.z + q0.w + q1.x + q1.y + q1.z + q1.w +
             q2.x + q2.y + q2.z + q2.w + q3.x + q3.y + q3.z + q3.w;
        int gp = pbase + tid;
        if (gp < m) out[gp] = r;
    }
}

// ---------------- launch ----------------

extern "C" void kernel_launch(void* const* d_in, const int* in_sizes, int n_in,
                              void* d_out, int out_size, void* d_ws, size_t ws_size,
                              hipStream_t stream) {
    const float* x   = (const float*)d_in[0];
    const int*   ei  = (const int*)d_in[1];
    const int*   eli = (const int*)d_in[2];
    const float* W   = (const float*)d_in[3];
    const float* bc  = (const float*)d_in[4];
    const float* W1  = (const float*)d_in[5];
    const float* b1  = (const float*)d_in[6];
    const float* w2  = (const float*)d_in[7];
    const float* b2  = (const float*)d_in[8];
    float* out = (float*)d_out;

    const int N = in_sizes[0] / N_CH;   // 50000
    const int E = in_sizes[1] / 2;      // 600000
    const int M = in_sizes[2] / 2;      // 200000

    const int* src = ei;
    const int* dst = ei + E;
    const int* ai  = eli;
    const int* bi  = eli + M;

    // workspace layout
    float* hA   = (float*)d_ws;                    // N*128
    float* hB   = hA + (size_t)N * N_CH;           // N*128
    int2*  csr2 = (int2*)(hB + (size_t)N * N_CH);  // E int2
    int*   cnt  = (int*)(csr2 + E);                // N
    int*   off  = cnt + N;                         // N
    int*   cur  = off + N;                         // N
    float* dnv  = (float*)(cur + N);               // N

    // 1) CSR by dst (with packed per-edge weights)
    k_zero<<<(N + 255) / 256, 256, 0, stream>>>(cnt, N);
    k_count<<<(E + 255) / 256, 256, 0, stream>>>(dst, cnt, E);
    k_scan<<<1, 1024, 0, stream>>>(cnt, off, cur, dnv, N);
    k_fill<<<(E + 255) / 256, 256, 0, stream>>>(src, dst, cur, dnv, csr2, E);

    // 2) two propagation hops
    int hop_blocks = (N + 3) / 4;
    k_hop<<<hop_blocks, 256, 0, stream>>>(x,  hA, off, cnt, dnv, csr2, N);
    k_hop<<<hop_blocks, 256, 0, stream>>>(hA, hB, off, cnt, dnv, csr2, N);

    // 3) z = hB @ W^T + bc  (into hA); tile grid: node-tiles x 2 ch-halves
    int ntiles = (N + 63) / 64;
    k_zlin<<<ntiles * 2, 256, 0, stream>>>(hB, W, bc, hA, N);

    // 4) decode (tiled GEMM, 64 pairs per block)
    k_decode<<<(M + 63) / 64, 256, 0, stream>>>(hA, ai, bi, W1, b1, w2, b2, out, M);
}